// Round 1
// baseline (1284.890 us; speedup 1.0000x reference)
//
#include <hip/hip_runtime.h>
#include <hip/hip_bf16.h>
#include <math.h>

// ---------------------------------------------------------------------------
// FakeNewsAttention round 3:
//  - M/Mt staged with global_load_lds (linear LDS dest, source-side XOR swizzle)
//    -> QK^T ds_reads no longer serialized behind staging vmcnt+ds_write.
//  - A rows T14-split: global->reg at iter top, reg->LDS after PV.
//  - ONE __syncthreads per iteration (lds_P is wave-private; only buffer flip
//    needs a barrier, and it also drains the in-flight global_load_lds DMA).
//  - lds_P XOR swizzle (col ^= q<<3) kills the 4-way P-write bank conflicts.
//  - s_setprio(1) around MFMA clusters.
//  - k_qproj: 16 users/block (Wcm re-reads 512MB -> 32MB L2).
//  - k_final: 512 threads/block (8 waves) for latency hiding.
// ---------------------------------------------------------------------------

#define S_TOT 50000
#define S_PAD 50304   // multiple of 64
#define DDIM 128
#define NHEAD 8
#define NB 1024
#define BQ 32         // batch rows per attention block
#define SN 32         // sources per inner iteration
#define NCH 16        // S chunks  -> grid = 16*32 = 512 blocks = 2/CU
#define SCHUNK 3136   // 16*3136 = 50176 >= 50000, multiple of 32
#define NIT (SCHUNK / SN)   // 98
#define NBT 32        // NB / BQ
#define PAD_CNT 176.0f      // 50176 - 50000 pad sources contribute exp(0)=1 each

typedef __bf16 v8bf __attribute__((ext_vector_type(8)));
typedef float v4f __attribute__((ext_vector_type(4)));

union U4BF { uint4 u; v8bf b; };

__device__ inline unsigned short f2bf(float f) {
  union { float f; unsigned u; } v; v.f = f;
  unsigned r = (v.u + 0x7FFFu + ((v.u >> 16) & 1u)) >> 16;
  return (unsigned short)r;
}

// global -> LDS direct DMA, 16B per lane; dest = wave-uniform base + lane*16
__device__ __forceinline__ void glld16(const void* g, void* l) {
  __builtin_amdgcn_global_load_lds((const __attribute__((address_space(1))) void*)g,
                                   (__attribute__((address_space(3))) void*)l, 16, 0, 0);
}

// ---------------------------------------------------------------- k_qproj
// 512 blocks (64 user-groups x 8 heads), 128 threads. Each block computes
// Q for 16 users of one head; Wcm[h] read once per block (32MB total, L2).
__global__ void k_qproj(const int* __restrict__ uid, const float* __restrict__ user_emb,
                        const float* __restrict__ Wcm, unsigned short* __restrict__ Qbf) {
  __shared__ float xu[16][DDIM];
  int h = blockIdx.x & 7, g = blockIdx.x >> 3;
  int e = threadIdx.x;          // 0..127
#pragma unroll
  for (int i = 0; i < 16; ++i)
    xu[i][e] = user_emb[(long)uid[(g << 4) + i] * DDIM + e];
  __syncthreads();
  float acc[16];
#pragma unroll
  for (int i = 0; i < 16; ++i) acc[i] = 0.f;
  const float* wp = Wcm + (long)h * DDIM * DDIM + e;
#pragma unroll 4
  for (int d = 0; d < DDIM; ++d) {
    float wv = wp[(long)d * DDIM];           // coalesced across lanes
#pragma unroll
    for (int i = 0; i < 16; ++i) acc[i] += xu[i][d] * wv;   // xu broadcast
  }
#pragma unroll
  for (int i = 0; i < 16; ++i)
    Qbf[((long)((g << 4) + i) * NHEAD + h) * DDIM + e] =
        f2bf(acc[i] * 0.08838834764831845f);  // 1/sqrt(128)
}

// ---------------------------------------------------------------- k_prepM
// fused: float M -> bf16 row-major Mbf (padded) + bf16 transposed MbfT
__global__ void k_prepM(const float* __restrict__ M, unsigned short* __restrict__ Mbf,
                        unsigned short* __restrict__ MbfT) {
  __shared__ unsigned short tile[64][66];   // 66: stride 132B = 33 banks -> 2-way free
  int s0 = blockIdx.x * 64, d0 = blockIdx.y * 64;
  int t = threadIdx.x;
#pragma unroll
  for (int it = 0; it < 16; ++it) {
    int flat = t + 256 * it;               // 0..4095
    int sl = flat >> 6, dl = flat & 63;
    int s = s0 + sl;
    float v = (s < S_TOT) ? M[(long)s * DDIM + d0 + dl] : 0.f;
    unsigned short bb = f2bf(v);
    tile[sl][dl] = bb;
    Mbf[(long)s * DDIM + d0 + dl] = bb;
  }
  __syncthreads();
#pragma unroll
  for (int it = 0; it < 16; ++it) {
    int flat = t + 256 * it;
    int dl = flat >> 6, sl = flat & 63;
    MbfT[(long)(d0 + dl) * S_PAD + s0 + sl] = tile[sl][dl];
  }
}

// ---------------------------------------------------------------- k_attn
// 512 threads = 8 waves; wave w == head w; BQ=32 batch rows.
// Double-buffered staging via global_load_lds + T14-split A; 1 sync/iter.
__launch_bounds__(512, 4)
__global__ void k_attn(const int* __restrict__ uid_g, const float* __restrict__ A_us,
                       const unsigned short* __restrict__ Qbf,
                       const unsigned short* __restrict__ Mbf,
                       const unsigned short* __restrict__ MbfT,
                       unsigned short* __restrict__ part_acc, float* __restrict__ part_sum) {
  // lds_M[buf][row][c16]: holds M[row][c16 ^ (row&7)] (16B units) -> 2-way reads
  __shared__ __align__(16) unsigned short lds_M[2][SN][DDIM];      // 16.0 KB
  // lds_Mt[buf][q][d][0..7] = MbfT[d][s0 + q*8 .. +7]   -> 2-way reads
  __shared__ __align__(16) unsigned short lds_Mt[2][4][DDIM][8];   // 16.0 KB
  // lds_P[row][col ^ (q(row)<<3)], q(row) = (row>>2)&3  -> conflict-free
  __shared__ __align__(16) unsigned short lds_P[256][40];          // 20.0 KB
  __shared__ __align__(16) float lds_At[2][SN][36];                //  9.2 KB
  __shared__ int lds_uid[BQ];                                      // ~62.6 KB total

  const int ch = blockIdx.x;   // 0..NCH-1
  const int bt = blockIdx.y;   // 0..NBT-1
  const int tid = threadIdx.x;
  const int w = tid >> 6;      // wave id == head
  const int lane = tid & 63;
  const int q = lane >> 4, li = lane & 15;

  if (tid < BQ) lds_uid[tid] = uid_g[bt * BQ + tid];

  // Q fragments (A-operand): qf[mt][k] -> Q[b0 + mt*16 + li][k*32 + q*8 .. +7]
  U4BF qf[2][4];
#pragma unroll
  for (int mt = 0; mt < 2; ++mt)
#pragma unroll
    for (int k = 0; k < 4; ++k) {
      int b = bt * BQ + mt * 16 + li;
      qf[mt][k].u = *(const uint4*)(Qbf + ((long)(b * NHEAD + w) * DDIM + k * 32 + q * 8));
    }

  v4f zero4 = {0.f, 0.f, 0.f, 0.f};
  v4f acc[2][8];
#pragma unroll
  for (int mt = 0; mt < 2; ++mt)
#pragma unroll
    for (int dt = 0; dt < 8; ++dt) acc[mt][dt] = zero4;
  float sE[2][4] = {{0.f,0.f,0.f,0.f},{0.f,0.f,0.f,0.f}};

  __syncthreads();   // lds_uid visible

  const int abl = tid >> 3, asq = (tid & 7) * 4;
  const float* arow = nullptr;
  if (tid < 256) arow = A_us + (long)lds_uid[abl] * S_TOT;

  const int s_beg = ch * SCHUNK;

  // issue M + Mt staging for tile starting at s0 into buf (pure DMA, no regs)
  auto mstage = [&](int buf, int s0) {
    {
      // wave w covers rows 4w..4w+3; lane l: row = 4w+(l>>4), stored col16 = l&15
      // source col16 = (l&15) ^ (row&7)  => LDS[row][c] = M[row][c^(row&7)]
      int srow = (w << 2) + (lane >> 4);
      int c16 = (lane & 15) ^ (srow & 7);
      glld16(Mbf + (long)(s0 + srow) * DDIM + (c16 << 3), &lds_M[buf][w << 2][0]);
    }
    {
      // wave w: qg = w>>1, d0 = (w&1)*64; lane l -> d = d0+l
      int qg = w >> 1, d0 = (w & 1) << 6;
      glld16(MbfT + (long)(d0 + lane) * S_PAD + s0 + (qg << 3), &lds_Mt[buf][qg][d0][0]);
    }
  };
  auto aload = [&](int s0, float4& av) {
    if (tid < 256) {
      int sg = s0 + asq;
      if (sg + 3 < S_TOT) {
        av = *(const float4*)(arow + sg);
      } else {
        av.x = (sg + 0 < S_TOT) ? arow[sg + 0] : 0.f;
        av.y = (sg + 1 < S_TOT) ? arow[sg + 1] : 0.f;
        av.z = (sg + 2 < S_TOT) ? arow[sg + 2] : 0.f;
        av.w = (sg + 3 < S_TOT) ? arow[sg + 3] : 0.f;
      }
    }
  };
  auto awrite = [&](int buf, const float4& av) {
    if (tid < 256) {
      lds_At[buf][asq + 0][abl] = av.x;
      lds_At[buf][asq + 1][abl] = av.y;
      lds_At[buf][asq + 2][abl] = av.z;
      lds_At[buf][asq + 3][abl] = av.w;
    }
  };

  // prologue: stage tile 0
  {
    float4 av = {0.f, 0.f, 0.f, 0.f};
    mstage(0, s_beg);
    aload(s_beg, av);
    awrite(0, av);
  }
  __syncthreads();   // drains vmcnt (DMA) + lgkm -> buf 0 ready

  for (int it = 0; it < NIT; ++it) {
    const int p = it & 1;
    const int s0 = s_beg + it * SN;
    float4 avn = {0.f, 0.f, 0.f, 0.f};
    if (it + 1 < NIT) {            // issue next-tile staging; lands across the iter
      mstage(1 - p, s0 + SN);
      aload(s0 + SN, avn);
    }

    // ---- QK^T from buf p (swizzled reads: 2-way = free) ----
    v4f c[2][2];
    c[0][0] = zero4; c[0][1] = zero4; c[1][0] = zero4; c[1][1] = zero4;
    __builtin_amdgcn_s_setprio(1);
#pragma unroll
    for (int k = 0; k < 4; ++k) {
      U4BF b0, b1;
      int r0 = li, r1 = 16 + li;
      b0.u = *(const uint4*)&lds_M[p][r0][(((k << 2) + q) ^ (r0 & 7)) << 3];
      b1.u = *(const uint4*)&lds_M[p][r1][(((k << 2) + q) ^ (r1 & 7)) << 3];
      c[0][0] = __builtin_amdgcn_mfma_f32_16x16x32_bf16(qf[0][k].b, b0.b, c[0][0], 0, 0, 0);
      c[0][1] = __builtin_amdgcn_mfma_f32_16x16x32_bf16(qf[0][k].b, b1.b, c[0][1], 0, 0, 0);
      c[1][0] = __builtin_amdgcn_mfma_f32_16x16x32_bf16(qf[1][k].b, b0.b, c[1][0], 0, 0, 0);
      c[1][1] = __builtin_amdgcn_mfma_f32_16x16x32_bf16(qf[1][k].b, b1.b, c[1][1], 0, 0, 0);
    }
    __builtin_amdgcn_s_setprio(0);

    // ---- P = exp(relu(score)*A); wave-private rows of lds_P, swizzled col ----
#pragma unroll
    for (int mt = 0; mt < 2; ++mt)
#pragma unroll
      for (int nt = 0; nt < 2; ++nt) {
        int sloc = nt * 16 + li;
        const float4 a4 = *(const float4*)&lds_At[p][sloc][(mt << 4) + (q << 2)];
        float aarr[4] = {a4.x, a4.y, a4.z, a4.w};
        int pcol = sloc ^ (q << 3);                    // swizzle: q = (row>>2)&3
        int prow = (w << 5) + (mt << 4) + (q << 2);
#pragma unroll
        for (int r = 0; r < 4; ++r) {
          float sc = fmaxf(c[mt][nt][r], 0.f) * aarr[r];
          float pv = __expf(sc);
          sE[mt][r] += pv;
          lds_P[prow + r][pcol] =
              (unsigned short)(__float_as_uint(pv) >> 16);  // truncation: bias cancels in ratio
        }
      }

    // ---- PV (no barrier: lds_P rows are this wave's; lgkmcnt orders RAW) ----
    U4BF pf[2];
    {
      int xq = (q ^ ((li >> 2) & 3)) << 3;             // un-swizzle for read row
      pf[0].u = *(const uint4*)&lds_P[(w << 5) + li][xq];
      pf[1].u = *(const uint4*)&lds_P[(w << 5) + 16 + li][xq];
    }
    __builtin_amdgcn_s_setprio(1);
#pragma unroll
    for (int dt = 0; dt < 8; ++dt) {
      U4BF mf;
      mf.u = *(const uint4*)&lds_Mt[p][q][dt * 16 + li][0];
      acc[0][dt] = __builtin_amdgcn_mfma_f32_16x16x32_bf16(pf[0].b, mf.b, acc[0][dt], 0, 0, 0);
      acc[1][dt] = __builtin_amdgcn_mfma_f32_16x16x32_bf16(pf[1].b, mf.b, acc[1][dt], 0, 0, 0);
    }
    __builtin_amdgcn_s_setprio(0);

    if (it + 1 < NIT) awrite(1 - p, avn);   // vmcnt wait here had the whole iter to fly

    __syncthreads();   // single barrier: drains DMA (next buf ready) + protects
                       // lds_P / lds_At[p] overwrite next iteration
  }

  // ---- write partials (bf16 acc, f32 sums) ----
  long base = ((long)ch * NBT + bt) * 256;
#pragma unroll
  for (int mt = 0; mt < 2; ++mt)
#pragma unroll
    for (int dt = 0; dt < 8; ++dt)
#pragma unroll
      for (int r = 0; r < 4; ++r) {
        int m = w * 32 + mt * 16 + q * 4 + r;
        part_acc[(base + m) * DDIM + dt * 16 + li] = f2bf(acc[mt][dt][r]);
      }
#pragma unroll
  for (int mt = 0; mt < 2; ++mt)
#pragma unroll
    for (int r = 0; r < 4; ++r) {
      float v = sE[mt][r];
      v += __shfl_xor(v, 1);
      v += __shfl_xor(v, 2);
      v += __shfl_xor(v, 4);
      v += __shfl_xor(v, 8);
      if (li == 0) part_sum[base + w * 32 + mt * 16 + q * 4 + r] = v;
    }
}

// ---------------------------------------------------------------- k_reduce
__global__ void k_reduce(const unsigned short* __restrict__ part_acc,
                         const float* __restrict__ part_sum, float* __restrict__ hhat) {
  int g = blockIdx.x * 256 + threadIdx.x;  // < 32*256*128
  int bt = g >> 15;
  int m = (g >> 7) & 255;
  int e = g & 127;
  float a = 0.f, s = 0.f;
#pragma unroll
  for (int ch = 0; ch < NCH; ++ch) {
    long base = ((long)ch * NBT + bt) * 256 + m;
    unsigned ub = part_acc[base * DDIM + e];
    a += __uint_as_float(ub << 16);
    s += part_sum[base];
  }
  s -= PAD_CNT;   // pad sources contributed exp(0)=1 each
  int h = m >> 5, bl = m & 31;
  int b = bt * BQ + bl;
  hhat[(long)b * 1024 + h * DDIM + e] = a / s;
}

// ---------------------------------------------------------------- k_final
// 256 blocks x 512 threads (8 waves): 4 b-rows/block, one row per 128-thread
// group; W1 stream shared via L1, 8 waves hide L2 latency.
__global__ void k_final(const float* __restrict__ hhat, const float* __restrict__ W1,
                        const int* __restrict__ uid, const float* __restrict__ user_emb,
                        float* __restrict__ out) {
  int d = threadIdx.x & 127;
  int sub = threadIdx.x >> 7;      // 0..3, wave-pair-uniform
  int b = (blockIdx.x << 2) + sub;
  const float* hr = hhat + (long)b * 1024;
  float a = 0.f;
#pragma unroll 8
  for (int k = 0; k < 1024; ++k)
    a += hr[k] * W1[(long)k * DDIM + d];
  float e = (a > 0.f) ? a : expm1f(a);
  out[(long)b * DDIM + d] = e + user_emb[(long)uid[b] * DDIM + d];
}

// ---------------------------------------------------------------- launch
extern "C" void kernel_launch(void* const* d_in, const int* in_sizes, int n_in,
                              void* d_out, int out_size, void* d_ws, size_t ws_size,
                              hipStream_t stream) {
  const int* uid        = (const int*)d_in[0];
  const float* user_emb = (const float*)d_in[1];
  const float* src_emb  = (const float*)d_in[2];
  const float* Wcm      = (const float*)d_in[3];
  const float* W1       = (const float*)d_in[4];
  const float* A_us     = (const float*)d_in[5];
  float* out = (float*)d_out;

  char* ws = (char*)d_ws;
  // workspace layout (bytes), total ~66.1 MB
  unsigned short* Qbf      = (unsigned short*)(ws + 0);          //  2,097,152
  unsigned short* Mbf      = (unsigned short*)(ws + 2097152);    // 12,877,824
  unsigned short* MbfT     = (unsigned short*)(ws + 14974976);   // 12,877,824
  unsigned short* part_acc = (unsigned short*)(ws + 27852800);   // 33,554,432 (bf16)
  float* part_sum          = (float*)(ws + 61407232);            //    524,288
  float* hhat              = (float*)(ws + 61931520);            //  4,194,304 -> 66,125,824

  k_qproj<<<dim3(NB / 16 * NHEAD), dim3(128), 0, stream>>>(uid, user_emb, Wcm, Qbf);
  k_prepM<<<dim3(S_PAD / 64, DDIM / 64), dim3(256), 0, stream>>>(src_emb, Mbf, MbfT);
  k_attn<<<dim3(NCH, NBT), dim3(512), 0, stream>>>(uid, A_us, Qbf, Mbf, MbfT, part_acc, part_sum);
  k_reduce<<<dim3(NBT * 256 * DDIM / 256), dim3(256), 0, stream>>>(part_acc, part_sum, hhat);
  k_final<<<dim3(256), dim3(512), 0, stream>>>(hhat, W1, uid, user_emb, out);
}